// Round 2
// baseline (2047.216 us; speedup 1.0000x reference)
//
#include <hip/hip_runtime.h>
#include <stdint.h>

// GraphTransformerLayer: B=32 T=128 N=42 E=256 H=8 DH=32. ALL float tensors are
// f32 (inputs AND outputs); distances int32. Round 2: correctness-first fused
// kernel, one block per (b,t) graph, VALU GEMMs, f32 accumulation throughout.

#define TPB 512
constexpr int BT = 4096;           // B*T
constexpr int N = 42, E = 256, H = 8, DH = 32;
constexpr int NE = N * E;          // 10752
constexpr int NN = N * N;          // 1764
constexpr int EP = E + 4;          // padded f32 row stride for Q/K/V (16B aligned)

__device__ __forceinline__ float b2f(uint16_t u) {
  union { uint32_t i; float f; } v; v.i = ((uint32_t)u) << 16; return v.f;
}
__device__ __forceinline__ uint16_t f2b(float f) {
  union { float f; uint32_t i; } v; v.f = f;
  uint32_t x = v.i;
  return (uint16_t)((x + 0x7fffu + ((x >> 16) & 1u)) >> 16);  // RNE
}

// out[n][e] = sum_k A[n][k]*W[k][e] + bias[e].
// A: bf16 in LDS (stride E). W/bias: f32 global. 8 waves; wave w owns rows
// n == w (mod 8); lane owns 4 consecutive e.
template <bool GOUT>
__device__ __forceinline__ void gemm_ne(const uint16_t* __restrict__ A,
                                        const float* __restrict__ W,
                                        const float* __restrict__ bias,
                                        float* __restrict__ outL,   // stride EP
                                        float* __restrict__ outG,   // stride E
                                        int w, int l) {
  const int e0 = l << 2;
  float acc[6][4];
#pragma unroll
  for (int r = 0; r < 6; ++r)
#pragma unroll
    for (int c = 0; c < 4; ++c) acc[r][c] = 0.f;

  for (int kc = 0; kc < E; kc += 8) {
    float wv[8][4];
#pragma unroll
    for (int i = 0; i < 8; ++i) {
      const float4 t = *(const float4*)(W + (kc + i) * E + e0);
      wv[i][0] = t.x; wv[i][1] = t.y; wv[i][2] = t.z; wv[i][3] = t.w;
    }
#pragma unroll
    for (int r = 0; r < 6; ++r) {
      const int n = w + (r << 3);
      if (n < N) {
        const ushort4 xa = *(const ushort4*)(A + n * E + kc);
        const ushort4 xb = *(const ushort4*)(A + n * E + kc + 4);
        const float x0 = b2f(xa.x), x1 = b2f(xa.y), x2 = b2f(xa.z), x3 = b2f(xa.w);
        const float x4 = b2f(xb.x), x5 = b2f(xb.y), x6 = b2f(xb.z), x7 = b2f(xb.w);
#pragma unroll
        for (int c = 0; c < 4; ++c) {
          acc[r][c] += x0 * wv[0][c] + x1 * wv[1][c] + x2 * wv[2][c] + x3 * wv[3][c]
                     + x4 * wv[4][c] + x5 * wv[5][c] + x6 * wv[6][c] + x7 * wv[7][c];
        }
      }
    }
  }
#pragma unroll
  for (int r = 0; r < 6; ++r) {
    const int n = w + (r << 3);
    if (n < N) {
      const float v0 = acc[r][0] + bias[e0 + 0];
      const float v1 = acc[r][1] + bias[e0 + 1];
      const float v2 = acc[r][2] + bias[e0 + 2];
      const float v3 = acc[r][3] + bias[e0 + 3];
      if (GOUT) {
        float4 o; o.x = v0; o.y = v1; o.z = v2; o.w = v3;
        *(float4*)(outG + n * E + e0) = o;
      } else {
        float4 o; o.x = v0; o.y = v1; o.z = v2; o.w = v3;
        *(float4*)(outL + n * EP + e0) = o;
      }
    }
  }
}

__global__ __launch_bounds__(TPB) void gt_kernel(
    const float* __restrict__ X, const float* __restrict__ adj,
    const int* __restrict__ dist,
    const float* __restrict__ Wq, const float* __restrict__ bq,
    const float* __restrict__ Wk, const float* __restrict__ bk,
    const float* __restrict__ Wv, const float* __restrict__ bv,
    const float* __restrict__ Wo, const float* __restrict__ bo,
    const float* __restrict__ rel,
    float* __restrict__ out, float* __restrict__ attn) {
  __shared__ uint16_t XO[N * E];   // X (bf16) during QKV; O (bf16) afterwards
  __shared__ float Qs[N * EP];
  __shared__ float Ks[N * EP];
  __shared__ float Vs[N * EP];
  __shared__ float Ss[N][44];      // padded score rows
  // total LDS: 21504 + 3*43680 + 7392 = 159936 B (<= 160 KiB)

  const int g = blockIdx.x;
  const int tid = threadIdx.x;
  const int w = tid >> 6, l = tid & 63;

  { // P1: stage X, f32 -> bf16
    const float4* src = (const float4*)(X + (size_t)g * NE);
    for (int i = tid; i * 4 < NE; i += TPB) {
      const float4 v = src[i];
      ushort4 o; o.x = f2b(v.x); o.y = f2b(v.y); o.z = f2b(v.z); o.w = f2b(v.w);
      *(ushort4*)(XO + i * 4) = o;
    }
  }
  __syncthreads();

  // P2: Q, K, V = X@W + b  (f32 in LDS)
  gemm_ne<false>(XO, Wq, bq, Qs, nullptr, w, l);
  gemm_ne<false>(XO, Wk, bk, Ks, nullptr, w, l);
  gemm_ne<false>(XO, Wv, bv, Vs, nullptr, w, l);
  __syncthreads();

  const float scale = 0.17677669529663687f;  // 1/sqrt(DH)
  for (int h = 0; h < H; ++h) {
    // scores + bias + mask
    for (int p = tid; p < NN; p += TPB) {
      const int i = p / N, j = p - i * N;
      const float4* qp = (const float4*)(Qs + i * EP + h * DH);
      const float4* kp = (const float4*)(Ks + j * EP + h * DH);
      float s = 0.f;
#pragma unroll
      for (int dd = 0; dd < 8; ++dd) {
        const float4 a = qp[dd], b = kp[dd];
        s += a.x * b.x + a.y * b.y + a.z * b.z + a.w * b.w;
      }
      const float am = adj[p];
      const float bi = rel[dist[p] * H + h];
      Ss[i][j] = (am > 0.f) ? (s * scale + bi) : -1e9f;
    }
    __syncthreads();

    // masked softmax per row; 4 lanes per row (groups aligned within a wave)
    {
      const int grp = tid >> 2, c = tid & 3;
      if (grp < N) {
        float m = -1e30f;
        for (int j = c; j < N; j += 4) m = fmaxf(m, Ss[grp][j]);
        m = fmaxf(m, __shfl_xor(m, 1));
        m = fmaxf(m, __shfl_xor(m, 2));
        float sum = 0.f;
        for (int j = c; j < N; j += 4) {
          const float p = __expf(Ss[grp][j] - m);  // masked: exp(-1e9-m) -> 0
          Ss[grp][j] = p;
          sum += p;
        }
        sum += __shfl_xor(sum, 1);
        sum += __shfl_xor(sum, 2);
        const float inv = 1.f / sum;
        for (int j = c; j < N; j += 4) Ss[grp][j] *= inv;
      }
    }
    __syncthreads();

    // attn output + O_h = P @ V_h (O stored bf16 in XO)
    const size_t abase = ((size_t)g * H + h) * (size_t)NN;
    for (int p = tid; p < NN; p += TPB) {
      const int i = p / N, j = p - i * N;
      attn[abase + p] = Ss[i][j];
    }
    for (int p = tid; p < N * 8; p += TPB) {  // 336 tasks: (row i, 4-wide d chunk)
      const int i = p >> 3, d4 = (p & 7) << 2;
      float a0 = 0.f, a1 = 0.f, a2 = 0.f, a3 = 0.f;
      for (int j = 0; j < N; ++j) {
        const float pr = Ss[i][j];
        const float4 vv = *(const float4*)(Vs + j * EP + h * DH + d4);
        a0 += pr * vv.x; a1 += pr * vv.y; a2 += pr * vv.z; a3 += pr * vv.w;
      }
      ushort4 o; o.x = f2b(a0); o.y = f2b(a1); o.z = f2b(a2); o.w = f2b(a3);
      *(ushort4*)(XO + i * E + h * DH + d4) = o;
    }
    __syncthreads();  // Ss/XO consumed before next head overwrites
  }

  // P4: out = O @ Wo + bo
  gemm_ne<true>(XO, Wo, bo, nullptr, out + (size_t)g * NE, w, l);
}

extern "C" void kernel_launch(void* const* d_in, const int* in_sizes, int n_in,
                              void* d_out, int out_size, void* d_ws, size_t ws_size,
                              hipStream_t stream) {
  const float* X    = (const float*)d_in[0];
  const float* adj  = (const float*)d_in[1];
  const int*   dist = (const int*)d_in[2];
  const float* Wq   = (const float*)d_in[3];
  const float* bq   = (const float*)d_in[4];
  const float* Wk   = (const float*)d_in[5];
  const float* bk   = (const float*)d_in[6];
  const float* Wv   = (const float*)d_in[7];
  const float* bv   = (const float*)d_in[8];
  const float* Wo   = (const float*)d_in[9];
  const float* bo   = (const float*)d_in[10];
  const float* rel  = (const float*)d_in[11];
  float* out  = (float*)d_out;
  float* attn = out + (size_t)BT * NE;

  gt_kernel<<<dim3(BT), dim3(TPB), 0, stream>>>(
      X, adj, dist, Wq, bq, Wk, bk, Wv, bv, Wo, bo, rel, out, attn);
}

// Round 3
// 543.290 us; speedup vs baseline: 3.7682x; 3.7682x over previous
//
#include <hip/hip_runtime.h>
#include <stdint.h>

// GraphTransformerLayer MI355X: B=32 T=128 N=42 E=256 H=8 DH=32, f32 I/O.
// Round 3: MFMA everywhere. Pre-pass: W -> bf16 W^T in d_ws. Main: one block
// per (b,t) graph, 8 waves; fused QKV MFMA GEMM; head-per-wave attention
// (QK^T MFMA, in-register softmax, PV MFMA via transposed V); Wo MFMA GEMM.

#define TPB 512
constexpr int BT = 4096;
constexpr int N = 42, NP = 48, E = 256, H = 8, DH = 32;
constexpr int NE = N * E;          // 10752
constexpr int NN = N * N;          // 1764
constexpr float SCALE = 0.17677669529663687f;  // 1/sqrt(32)

typedef short sh8 __attribute__((ext_vector_type(8)));   // 8 bf16 (4 VGPR)
typedef float f4 __attribute__((ext_vector_type(4)));    // MFMA C/D frag

__device__ __forceinline__ float b2f(uint16_t u) {
  union { uint32_t i; float f; } v; v.i = ((uint32_t)u) << 16; return v.f;
}
__device__ __forceinline__ uint16_t f2b(float f) {
  union { float f; uint32_t i; } v; v.f = f;
  const uint32_t x = v.i;
  return (uint16_t)((x + 0x7fffu + ((x >> 16) & 1u)) >> 16);  // RNE
}

// XOR swizzle for row-major bf16 [*][256] LDS tiles (512B row stride):
// spreads 16 rows across 8 16B bank-slots -> 2-way (free) on ds_read_b128.
#define SWZ(base, row, cb) \
  ((char*)(base) + ((((row) << 9) + (cb)) ^ (((row) & 7) << 4)))

// ---- pre-pass: WT[n][k] = bf16(W[k][n]), 4 matrices -------------------------
__global__ __launch_bounds__(256) void wt_kernel(
    const float* __restrict__ Wq, const float* __restrict__ Wk,
    const float* __restrict__ Wv, const float* __restrict__ Wo,
    uint16_t* __restrict__ WT) {
  __shared__ float tl[32][33];
  const int z = blockIdx.z;
  const float* W = (z == 0) ? Wq : (z == 1) ? Wk : (z == 2) ? Wv : Wo;
  uint16_t* dst = WT + z * 65536;
  const int k0 = blockIdx.y * 32, n0 = blockIdx.x * 32;
  const int r = threadIdx.x >> 5, cc = threadIdx.x & 31;
#pragma unroll
  for (int p = 0; p < 4; ++p)
    tl[r + 8 * p][cc] = W[(k0 + r + 8 * p) * E + n0 + cc];
  __syncthreads();
#pragma unroll
  for (int p = 0; p < 4; ++p)
    dst[(n0 + r + 8 * p) * E + k0 + cc] = f2b(tl[cc][r + 8 * p]);
}

// ---- main fused kernel ------------------------------------------------------
__global__ __launch_bounds__(TPB, 2) void gt_kernel(
    const float* __restrict__ X, const float* __restrict__ adj,
    const int* __restrict__ dist,
    const float* __restrict__ bq, const float* __restrict__ bk,
    const float* __restrict__ bv, const float* __restrict__ bo,
    const float* __restrict__ rel, const uint16_t* __restrict__ WT,
    float* __restrict__ out, float* __restrict__ attn) {
  alignas(16) __shared__ uint16_t Xb[NP * E];     // X bf16 (QKV); O bf16 (Wo)
  alignas(16) __shared__ uint16_t Qb[NP * E];
  alignas(16) __shared__ uint16_t Kb[NP * E];
  alignas(16) __shared__ uint16_t VT[E * 56];     // V transposed [d][i]
  alignas(16) __shared__ uint16_t Ps[8 * NP * 56];// per-wave P bf16 [i][j]
  __shared__ uint8_t dm8[NP * NP];                // dist | (mask<<7)
  __shared__ float relL[120];
  // LDS: 3*24576 + 28672 + 43008 + 2304 + 480 = 148192 B

  const int gid = blockIdx.x;
  const int tid = threadIdx.x;
  const int w = tid >> 6, lane = tid & 63, c = lane & 15, lg = lane >> 4;

  const uint16_t* WTq = WT;
  const uint16_t* WTk = WT + 65536;
  const uint16_t* WTv = WT + 131072;
  const uint16_t* WTo = WT + 196608;

  // ---- P1: stage X (f32->bf16, swizzled), pad rows, mask/dist table, rel ----
  {
    const float2* Xs = (const float2*)(X + (size_t)gid * NE);
    for (int i = tid; i < NE / 2; i += TPB) {
      const float2 v = Xs[i];
      const int row = i >> 7, cb = (i & 127) << 2;
      const uint32_t pk = (uint32_t)f2b(v.x) | ((uint32_t)f2b(v.y) << 16);
      *(uint32_t*)SWZ(Xb, row, cb) = pk;
    }
    for (int i = tid; i < (NP - N) * 128; i += TPB) {
      const int row = N + (i >> 7), cb = (i & 127) << 2;
      *(uint32_t*)SWZ(Xb, row, cb) = 0u;
    }
    for (int t = tid; t < NP * NP; t += TPB) {
      const int i = t / NP, j = t - i * NP;
      uint8_t v = 0;
      if (i < N && j < N) {
        const float a = adj[i * N + j];
        const int d = dist[i * N + j];
        v = (uint8_t)d | (a > 0.f ? 0x80 : 0);
      }
      dm8[t] = v;
    }
    for (int t = tid; t < 120; t += TPB) relL[t] = rel[t];
  }
  __syncthreads();

  // ---- P2: fused QKV GEMM. wave w owns col-tiles nt0=2w,2w+1; 3 row-tiles --
  const int nt0 = 2 * w;
  f4 aQ[3][2], aK[3][2], aV[3][2];
#pragma unroll
  for (int mt = 0; mt < 3; ++mt)
#pragma unroll
    for (int nt = 0; nt < 2; ++nt) {
      aQ[mt][nt] = (f4){0.f, 0.f, 0.f, 0.f};
      aK[mt][nt] = (f4){0.f, 0.f, 0.f, 0.f};
      aV[mt][nt] = (f4){0.f, 0.f, 0.f, 0.f};
    }
  for (int kc = 0; kc < E; kc += 32) {
    sh8 xa[3];
#pragma unroll
    for (int mt = 0; mt < 3; ++mt)
      xa[mt] = *(const sh8*)SWZ(Xb, 16 * mt + c, (kc + 8 * lg) * 2);
#pragma unroll
    for (int nt = 0; nt < 2; ++nt) {
      const int n = (nt0 + nt) * 16 + c;
      const int ko = n * E + kc + 8 * lg;
      const sh8 bq8 = *(const sh8*)(WTq + ko);
      const sh8 bk8 = *(const sh8*)(WTk + ko);
      const sh8 bv8 = *(const sh8*)(WTv + ko);
#pragma unroll
      for (int mt = 0; mt < 3; ++mt) {
        aQ[mt][nt] = __builtin_amdgcn_mfma_f32_16x16x32_bf16(xa[mt], bq8, aQ[mt][nt], 0, 0, 0);
        aK[mt][nt] = __builtin_amdgcn_mfma_f32_16x16x32_bf16(xa[mt], bk8, aK[mt][nt], 0, 0, 0);
        aV[mt][nt] = __builtin_amdgcn_mfma_f32_16x16x32_bf16(xa[mt], bv8, aV[mt][nt], 0, 0, 0);
      }
    }
  }
  // epilogue: Q,K -> swizzled bf16 rows; V -> transposed VT[d][i]
#pragma unroll
  for (int nt = 0; nt < 2; ++nt) {
    const int n = (nt0 + nt) * 16 + c;
    const float bqv = bq[n], bkv = bk[n], bvv = bv[n];
#pragma unroll
    for (int mt = 0; mt < 3; ++mt) {
      uint16_t vr[4];
#pragma unroll
      for (int r = 0; r < 4; ++r) {
        const int i = 16 * mt + 4 * lg + r;
        *(uint16_t*)SWZ(Qb, i, n * 2) = f2b(aQ[mt][nt][r] + bqv);
        *(uint16_t*)SWZ(Kb, i, n * 2) = f2b(aK[mt][nt][r] + bkv);
        vr[r] = f2b(aV[mt][nt][r] + bvv);
      }
      ushort4 vv; vv.x = vr[0]; vv.y = vr[1]; vv.z = vr[2]; vv.w = vr[3];
      *(ushort4*)(VT + n * 56 + 16 * mt + 4 * lg) = vv;
    }
  }
  __syncthreads();

  // ---- P3: attention, head h = wave id -------------------------------------
  {
    const int h = w;
    sh8 qa[3], kb8[3];
#pragma unroll
    for (int t = 0; t < 3; ++t) {
      qa[t] = *(const sh8*)SWZ(Qb, 16 * t + c, (h * 32 + 8 * lg) * 2);
      kb8[t] = *(const sh8*)SWZ(Kb, 16 * t + c, (h * 32 + 8 * lg) * 2);
    }
    f4 st[3][3];
#pragma unroll
    for (int mt = 0; mt < 3; ++mt)
#pragma unroll
      for (int nt = 0; nt < 3; ++nt) {
        st[mt][nt] = (f4){0.f, 0.f, 0.f, 0.f};
        st[mt][nt] = __builtin_amdgcn_mfma_f32_16x16x32_bf16(qa[mt], kb8[nt], st[mt][nt], 0, 0, 0);
      }

    const size_t abase = ((size_t)gid * H + h) * (size_t)NN;
    uint16_t* Psw = Ps + w * NP * 56;
#pragma unroll
    for (int mt = 0; mt < 3; ++mt)
#pragma unroll
      for (int r = 0; r < 4; ++r) {
        const int i = 16 * mt + 4 * lg + r;
        float sv[3];
#pragma unroll
        for (int nt = 0; nt < 3; ++nt) {
          const int j = 16 * nt + c;
          const uint8_t dm = dm8[i * NP + j];
          sv[nt] = (dm & 0x80) ? st[mt][nt][r] * SCALE + relL[(dm & 0x7f) * 8 + h]
                               : -1e9f;
        }
        float m = fmaxf(fmaxf(sv[0], sv[1]), sv[2]);
        m = fmaxf(m, __shfl_xor(m, 1));
        m = fmaxf(m, __shfl_xor(m, 2));
        m = fmaxf(m, __shfl_xor(m, 4));
        m = fmaxf(m, __shfl_xor(m, 8));
        float p0 = __expf(sv[0] - m), p1 = __expf(sv[1] - m), p2 = __expf(sv[2] - m);
        float sum = p0 + p1 + p2;
        sum += __shfl_xor(sum, 1);
        sum += __shfl_xor(sum, 2);
        sum += __shfl_xor(sum, 4);
        sum += __shfl_xor(sum, 8);
        const float inv = __builtin_amdgcn_rcpf(sum);
        p0 *= inv; p1 *= inv; p2 *= inv;
        const float pv[3] = {p0, p1, p2};
#pragma unroll
        for (int nt = 0; nt < 3; ++nt) {
          const int j = 16 * nt + c;
          if (i < N && j < N) attn[abase + i * N + j] = pv[nt];
          Psw[i * 56 + j] = f2b(pv[nt]);
        }
      }

    // PV: O_h = P @ V_h   (A = P rows from Psw, B = V^T rows from VT)
    const sh8 z8 = {0, 0, 0, 0, 0, 0, 0, 0};
    sh8 pa0[3], pa1[3], vb0[2], vb1[2];
#pragma unroll
    for (int mt = 0; mt < 3; ++mt) {
      pa0[mt] = *(const sh8*)(Psw + (16 * mt + c) * 56 + 8 * lg);
      pa1[mt] = (lg < 2) ? *(const sh8*)(Psw + (16 * mt + c) * 56 + 32 + 8 * lg) : z8;
    }
#pragma unroll
    for (int nt = 0; nt < 2; ++nt) {
      const int d = h * 32 + 16 * nt + c;
      vb0[nt] = *(const sh8*)(VT + d * 56 + 8 * lg);
      vb1[nt] = (lg < 2) ? *(const sh8*)(VT + d * 56 + 32 + 8 * lg) : z8;
    }
    f4 ov[3][2];
#pragma unroll
    for (int mt = 0; mt < 3; ++mt)
#pragma unroll
      for (int nt = 0; nt < 2; ++nt) {
        ov[mt][nt] = (f4){0.f, 0.f, 0.f, 0.f};
        ov[mt][nt] = __builtin_amdgcn_mfma_f32_16x16x32_bf16(pa0[mt], vb0[nt], ov[mt][nt], 0, 0, 0);
        ov[mt][nt] = __builtin_amdgcn_mfma_f32_16x16x32_bf16(pa1[mt], vb1[nt], ov[mt][nt], 0, 0, 0);
      }
#pragma unroll
    for (int mt = 0; mt < 3; ++mt)
#pragma unroll
      for (int nt = 0; nt < 2; ++nt)
#pragma unroll
        for (int r = 0; r < 4; ++r) {
          const int i = 16 * mt + 4 * lg + r;
          const int dn = h * 32 + 16 * nt + c;
          *(uint16_t*)SWZ(Xb, i, dn * 2) = f2b(ov[mt][nt][r]);
        }
  }
  __syncthreads();

  // ---- P4: out = O @ Wo + bo ------------------------------------------------
  {
    f4 ao[3][2];
#pragma unroll
    for (int mt = 0; mt < 3; ++mt)
#pragma unroll
      for (int nt = 0; nt < 2; ++nt) ao[mt][nt] = (f4){0.f, 0.f, 0.f, 0.f};
    for (int kc = 0; kc < E; kc += 32) {
      sh8 xa[3];
#pragma unroll
      for (int mt = 0; mt < 3; ++mt)
        xa[mt] = *(const sh8*)SWZ(Xb, 16 * mt + c, (kc + 8 * lg) * 2);
#pragma unroll
      for (int nt = 0; nt < 2; ++nt) {
        const int n = (nt0 + nt) * 16 + c;
        const sh8 b8 = *(const sh8*)(WTo + n * E + kc + 8 * lg);
#pragma unroll
        for (int mt = 0; mt < 3; ++mt)
          ao[mt][nt] = __builtin_amdgcn_mfma_f32_16x16x32_bf16(xa[mt], b8, ao[mt][nt], 0, 0, 0);
      }
    }
#pragma unroll
    for (int nt = 0; nt < 2; ++nt) {
      const int n = (nt0 + nt) * 16 + c;
      const float bov = bo[n];
#pragma unroll
      for (int mt = 0; mt < 3; ++mt)
#pragma unroll
        for (int r = 0; r < 4; ++r) {
          const int i = 16 * mt + 4 * lg + r;
          if (i < N) out[(size_t)gid * NE + i * E + n] = ao[mt][nt][r] + bov;
        }
    }
  }
}

extern "C" void kernel_launch(void* const* d_in, const int* in_sizes, int n_in,
                              void* d_out, int out_size, void* d_ws, size_t ws_size,
                              hipStream_t stream) {
  const float* X    = (const float*)d_in[0];
  const float* adj  = (const float*)d_in[1];
  const int*   dist = (const int*)d_in[2];
  const float* Wq   = (const float*)d_in[3];
  const float* bq   = (const float*)d_in[4];
  const float* Wk   = (const float*)d_in[5];
  const float* bk   = (const float*)d_in[6];
  const float* Wv   = (const float*)d_in[7];
  const float* bv   = (const float*)d_in[8];
  const float* Wo   = (const float*)d_in[9];
  const float* bo   = (const float*)d_in[10];
  const float* rel  = (const float*)d_in[11];
  float* out  = (float*)d_out;
  float* attn = out + (size_t)BT * NE;
  uint16_t* WT = (uint16_t*)d_ws;  // 4 * 256*256 bf16 = 512 KB

  wt_kernel<<<dim3(8, 8, 4), dim3(256), 0, stream>>>(Wq, Wk, Wv, Wo, WT);
  gt_kernel<<<dim3(BT), dim3(TPB), 0, stream>>>(
      X, adj, dist, bq, bk, bv, bo, rel, WT, out, attn);
}

// Round 4
// 439.562 us; speedup vs baseline: 4.6574x; 1.2360x over previous
//
#include <hip/hip_runtime.h>
#include <stdint.h>

// GraphTransformerLayer MI355X: B=32 T=128 N=42 E=256 H=8 DH=32, f32 I/O.
// Round 4: LDS aliasing (76.5 KB -> 2 blocks/CU), coalesced attn stores from
// LDS-staged bf16 P. Same MFMA structure as round 3.

#define TPB 512
constexpr int BT = 4096;
constexpr int N = 42, NP = 48, E = 256, H = 8, DH = 32;
constexpr int NE = N * E;          // 10752
constexpr int NN = N * N;          // 1764
constexpr float SCALE = 0.17677669529663687f;  // 1/sqrt(32)

typedef short sh8 __attribute__((ext_vector_type(8)));   // 8 bf16 (4 VGPR)
typedef float f4 __attribute__((ext_vector_type(4)));    // MFMA C/D frag

__device__ __forceinline__ float b2f(uint16_t u) {
  union { uint32_t i; float f; } v; v.i = ((uint32_t)u) << 16; return v.f;
}
__device__ __forceinline__ uint16_t f2b(float f) {
  union { float f; uint32_t i; } v; v.f = f;
  const uint32_t x = v.i;
  return (uint16_t)((x + 0x7fffu + ((x >> 16) & 1u)) >> 16);  // RNE
}

// XOR swizzle for row-major bf16 [*][256] LDS tiles (512B row stride).
#define SWZ(base, row, cb) \
  ((char*)(base) + ((((row) << 9) + (cb)) ^ (((row) & 7) << 4)))

// ---- pre-pass: WT[n][k] = bf16(W[k][n]), 4 matrices -------------------------
__global__ __launch_bounds__(256) void wt_kernel(
    const float* __restrict__ Wq, const float* __restrict__ Wk,
    const float* __restrict__ Wv, const float* __restrict__ Wo,
    uint16_t* __restrict__ WT) {
  __shared__ float tl[32][33];
  const int z = blockIdx.z;
  const float* W = (z == 0) ? Wq : (z == 1) ? Wk : (z == 2) ? Wv : Wo;
  uint16_t* dst = WT + z * 65536;
  const int k0 = blockIdx.y * 32, n0 = blockIdx.x * 32;
  const int r = threadIdx.x >> 5, cc = threadIdx.x & 31;
#pragma unroll
  for (int p = 0; p < 4; ++p)
    tl[r + 8 * p][cc] = W[(k0 + r + 8 * p) * E + n0 + cc];
  __syncthreads();
#pragma unroll
  for (int p = 0; p < 4; ++p)
    dst[(n0 + r + 8 * p) * E + k0 + cc] = f2b(tl[cc][r + 8 * p]);
}

// ---- main fused kernel ------------------------------------------------------
// LDS map (76512 B total -> 2 blocks/CU):
//   R1 [0,24576):      Xb (swizzled [48][256])  ->  VT ([256][48])  ->  O (swizzled)
//   R2 [24576,49152):  Qb (swizzled)            ->  Ps[0:24576)
//   R3 [49152,73728):  Kb (swizzled)            ->  Ps[24576:43008)
//   dm8 [73728,76032), relL [76032,76512)
__global__ __launch_bounds__(TPB, 4) void gt_kernel(
    const float* __restrict__ X, const float* __restrict__ adj,
    const int* __restrict__ dist,
    const float* __restrict__ bq, const float* __restrict__ bk,
    const float* __restrict__ bv, const float* __restrict__ bo,
    const float* __restrict__ rel, const uint16_t* __restrict__ WT,
    float* __restrict__ out, float* __restrict__ attn) {
  alignas(16) __shared__ char smem[76512];
  uint16_t* const Xb = (uint16_t*)smem;                 // also O
  uint16_t* const VT = (uint16_t*)smem;                 // [256][48]
  uint16_t* const Qb = (uint16_t*)(smem + 24576);
  uint16_t* const Kb = (uint16_t*)(smem + 49152);
  uint16_t* const Ps = (uint16_t*)(smem + 24576);       // per-wave [48][56]
  uint8_t*  const dm8 = (uint8_t*)(smem + 73728);       // dist | (mask<<7)
  float*    const relL = (float*)(smem + 76032);

  const int gid = blockIdx.x;
  const int tid = threadIdx.x;
  const int w = tid >> 6, lane = tid & 63, c = lane & 15, lg = lane >> 4;

  const uint16_t* WTq = WT;
  const uint16_t* WTk = WT + 65536;
  const uint16_t* WTv = WT + 131072;
  const uint16_t* WTo = WT + 196608;

  // ---- P1: stage X (f32->bf16, swizzled), pad rows, mask/dist table, rel ----
  {
    const float2* Xs = (const float2*)(X + (size_t)gid * NE);
    for (int i = tid; i < NE / 2; i += TPB) {
      const float2 v = Xs[i];
      const int row = i >> 7, cb = (i & 127) << 2;
      const uint32_t pk = (uint32_t)f2b(v.x) | ((uint32_t)f2b(v.y) << 16);
      *(uint32_t*)SWZ(Xb, row, cb) = pk;
    }
    for (int i = tid; i < (NP - N) * 128; i += TPB) {
      const int row = N + (i >> 7), cb = (i & 127) << 2;
      *(uint32_t*)SWZ(Xb, row, cb) = 0u;
    }
    for (int t = tid; t < NP * NP; t += TPB) {
      const int i = t / NP, j = t - i * NP;
      uint8_t v = 0;
      if (i < N && j < N) {
        const float a = adj[i * N + j];
        const int d = dist[i * N + j];
        v = (uint8_t)d | (a > 0.f ? 0x80 : 0);
      }
      dm8[t] = v;
    }
    for (int t = tid; t < 120; t += TPB) relL[t] = rel[t];
  }
  __syncthreads();  // b1

  // ---- P2: fused QKV GEMM. wave w owns col-tiles nt0=2w,2w+1; 3 row-tiles --
  const int nt0 = 2 * w;
  f4 aQ[3][2], aK[3][2], aV[3][2];
#pragma unroll
  for (int mt = 0; mt < 3; ++mt)
#pragma unroll
    for (int nt = 0; nt < 2; ++nt) {
      aQ[mt][nt] = (f4){0.f, 0.f, 0.f, 0.f};
      aK[mt][nt] = (f4){0.f, 0.f, 0.f, 0.f};
      aV[mt][nt] = (f4){0.f, 0.f, 0.f, 0.f};
    }
  for (int kc = 0; kc < E; kc += 32) {
    sh8 xa[3];
#pragma unroll
    for (int mt = 0; mt < 3; ++mt)
      xa[mt] = *(const sh8*)SWZ(Xb, 16 * mt + c, (kc + 8 * lg) * 2);
#pragma unroll
    for (int nt = 0; nt < 2; ++nt) {
      const int n = (nt0 + nt) * 16 + c;
      const int ko = n * E + kc + 8 * lg;
      const sh8 bq8 = *(const sh8*)(WTq + ko);
      const sh8 bk8 = *(const sh8*)(WTk + ko);
      const sh8 bv8 = *(const sh8*)(WTv + ko);
#pragma unroll
      for (int mt = 0; mt < 3; ++mt) {
        aQ[mt][nt] = __builtin_amdgcn_mfma_f32_16x16x32_bf16(xa[mt], bq8, aQ[mt][nt], 0, 0, 0);
        aK[mt][nt] = __builtin_amdgcn_mfma_f32_16x16x32_bf16(xa[mt], bk8, aK[mt][nt], 0, 0, 0);
        aV[mt][nt] = __builtin_amdgcn_mfma_f32_16x16x32_bf16(xa[mt], bv8, aV[mt][nt], 0, 0, 0);
      }
    }
  }
  __syncthreads();  // b2: all X reads done before VT overwrites R1

  // epilogue: Q,K -> swizzled bf16 rows; V -> transposed VT[d][k]
#pragma unroll
  for (int nt = 0; nt < 2; ++nt) {
    const int n = (nt0 + nt) * 16 + c;
    const float bqv = bq[n], bkv = bk[n], bvv = bv[n];
#pragma unroll
    for (int mt = 0; mt < 3; ++mt) {
      uint16_t vr[4];
#pragma unroll
      for (int r = 0; r < 4; ++r) {
        const int i = 16 * mt + 4 * lg + r;
        *(uint16_t*)SWZ(Qb, i, n * 2) = f2b(aQ[mt][nt][r] + bqv);
        *(uint16_t*)SWZ(Kb, i, n * 2) = f2b(aK[mt][nt][r] + bkv);
        vr[r] = f2b(aV[mt][nt][r] + bvv);
      }
      ushort4 vv; vv.x = vr[0]; vv.y = vr[1]; vv.z = vr[2]; vv.w = vr[3];
      *(ushort4*)(VT + n * 48 + 16 * mt + 4 * lg) = vv;
    }
  }
  __syncthreads();  // b3

  // ---- P3: attention, head h = wave id -------------------------------------
  {
    const int h = w;
    sh8 qa[3], kb8[3];
#pragma unroll
    for (int t = 0; t < 3; ++t) {
      qa[t] = *(const sh8*)SWZ(Qb, 16 * t + c, (h * 32 + 8 * lg) * 2);
      kb8[t] = *(const sh8*)SWZ(Kb, 16 * t + c, (h * 32 + 8 * lg) * 2);
    }
    __syncthreads();  // b4: frag loads done before Ps overwrites R2/R3

    f4 st[3][3];
#pragma unroll
    for (int mt = 0; mt < 3; ++mt)
#pragma unroll
      for (int nt = 0; nt < 3; ++nt) {
        st[mt][nt] = (f4){0.f, 0.f, 0.f, 0.f};
        st[mt][nt] = __builtin_amdgcn_mfma_f32_16x16x32_bf16(qa[mt], kb8[nt], st[mt][nt], 0, 0, 0);
      }

    uint16_t* Psw = Ps + w * 2688;  // [48][56] bf16
#pragma unroll
    for (int mt = 0; mt < 3; ++mt)
#pragma unroll
      for (int r = 0; r < 4; ++r) {
        const int i = 16 * mt + 4 * lg + r;
        float sv[3];
#pragma unroll
        for (int nt = 0; nt < 3; ++nt) {
          const int j = 16 * nt + c;
          const uint8_t dm = dm8[i * NP + j];
          sv[nt] = (dm & 0x80) ? st[mt][nt][r] * SCALE + relL[(dm & 0x7f) * 8 + h]
                               : -1e9f;
        }
        float m = fmaxf(fmaxf(sv[0], sv[1]), sv[2]);
        m = fmaxf(m, __shfl_xor(m, 1));
        m = fmaxf(m, __shfl_xor(m, 2));
        m = fmaxf(m, __shfl_xor(m, 4));
        m = fmaxf(m, __shfl_xor(m, 8));
        float p0 = __expf(sv[0] - m), p1 = __expf(sv[1] - m), p2 = __expf(sv[2] - m);
        float sum = p0 + p1 + p2;
        sum += __shfl_xor(sum, 1);
        sum += __shfl_xor(sum, 2);
        sum += __shfl_xor(sum, 4);
        sum += __shfl_xor(sum, 8);
        const float inv = __builtin_amdgcn_rcpf(sum);
        Psw[i * 56 + 16 * 0 + c] = f2b(p0 * inv);
        Psw[i * 56 + 16 * 1 + c] = f2b(p1 * inv);
        Psw[i * 56 + 16 * 2 + c] = f2b(p2 * inv);
      }

    // coalesced attn store from staged bf16 P (wave-private region)
    {
      const size_t abase = ((size_t)gid * H + h) * (size_t)NN;
      for (int p = lane; p < NN; p += 64) {
        const int i = p / N, j = p - i * N;
        attn[abase + p] = b2f(Psw[i * 56 + j]);
      }
    }

    // PV: O_h = P @ V_h   (A = P rows from Psw, B = V^T rows from VT)
    const sh8 z8 = {0, 0, 0, 0, 0, 0, 0, 0};
    sh8 pa0[3], pa1[3], vb0[2], vb1[2];
#pragma unroll
    for (int mt = 0; mt < 3; ++mt) {
      pa0[mt] = *(const sh8*)(Psw + (16 * mt + c) * 56 + 8 * lg);
      pa1[mt] = (lg < 2) ? *(const sh8*)(Psw + (16 * mt + c) * 56 + 32 + 8 * lg) : z8;
    }
#pragma unroll
    for (int nt = 0; nt < 2; ++nt) {
      const int d = h * 32 + 16 * nt + c;
      vb0[nt] = *(const sh8*)(VT + d * 48 + 8 * lg);
      vb1[nt] = (lg < 2) ? *(const sh8*)(VT + d * 48 + 32 + 8 * lg) : z8;
    }
    f4 ov[3][2];
#pragma unroll
    for (int mt = 0; mt < 3; ++mt)
#pragma unroll
      for (int nt = 0; nt < 2; ++nt) {
        ov[mt][nt] = (f4){0.f, 0.f, 0.f, 0.f};
        ov[mt][nt] = __builtin_amdgcn_mfma_f32_16x16x32_bf16(pa0[mt], vb0[nt], ov[mt][nt], 0, 0, 0);
        ov[mt][nt] = __builtin_amdgcn_mfma_f32_16x16x32_bf16(pa1[mt], vb1[nt], ov[mt][nt], 0, 0, 0);
      }
    __syncthreads();  // b5: all VT reads done before O overwrites R1
#pragma unroll
    for (int mt = 0; mt < 3; ++mt)
#pragma unroll
      for (int nt = 0; nt < 2; ++nt)
#pragma unroll
        for (int r = 0; r < 4; ++r) {
          const int i = 16 * mt + 4 * lg + r;
          const int dn = h * 32 + 16 * nt + c;
          *(uint16_t*)SWZ(Xb, i, dn * 2) = f2b(ov[mt][nt][r]);
        }
  }
  __syncthreads();  // b6

  // ---- P4: out = O @ Wo + bo ------------------------------------------------
  {
    f4 ao[3][2];
#pragma unroll
    for (int mt = 0; mt < 3; ++mt)
#pragma unroll
      for (int nt = 0; nt < 2; ++nt) ao[mt][nt] = (f4){0.f, 0.f, 0.f, 0.f};
    for (int kc = 0; kc < E; kc += 32) {
      sh8 xa[3];
#pragma unroll
      for (int mt = 0; mt < 3; ++mt)
        xa[mt] = *(const sh8*)SWZ(Xb, 16 * mt + c, (kc + 8 * lg) * 2);
#pragma unroll
      for (int nt = 0; nt < 2; ++nt) {
        const int n = (nt0 + nt) * 16 + c;
        const sh8 b8 = *(const sh8*)(WTo + n * E + kc + 8 * lg);
#pragma unroll
        for (int mt = 0; mt < 3; ++mt)
          ao[mt][nt] = __builtin_amdgcn_mfma_f32_16x16x32_bf16(xa[mt], b8, ao[mt][nt], 0, 0, 0);
      }
    }
#pragma unroll
    for (int nt = 0; nt < 2; ++nt) {
      const int n = (nt0 + nt) * 16 + c;
      const float bov = bo[n];
#pragma unroll
      for (int mt = 0; mt < 3; ++mt)
#pragma unroll
        for (int r = 0; r < 4; ++r) {
          const int i = 16 * mt + 4 * lg + r;
          if (i < N) out[(size_t)gid * NE + i * E + n] = ao[mt][nt][r] + bov;
        }
    }
  }
}

extern "C" void kernel_launch(void* const* d_in, const int* in_sizes, int n_in,
                              void* d_out, int out_size, void* d_ws, size_t ws_size,
                              hipStream_t stream) {
  const float* X    = (const float*)d_in[0];
  const float* adj  = (const float*)d_in[1];
  const int*   dist = (const int*)d_in[2];
  const float* Wq   = (const float*)d_in[3];
  const float* bq   = (const float*)d_in[4];
  const float* Wk   = (const float*)d_in[5];
  const float* bk   = (const float*)d_in[6];
  const float* Wv   = (const float*)d_in[7];
  const float* bv   = (const float*)d_in[8];
  const float* Wo   = (const float*)d_in[9];
  const float* bo   = (const float*)d_in[10];
  const float* rel  = (const float*)d_in[11];
  float* out  = (float*)d_out;
  float* attn = out + (size_t)BT * NE;
  uint16_t* WT = (uint16_t*)d_ws;  // 4 * 256*256 bf16 = 512 KB

  wt_kernel<<<dim3(8, 8, 4), dim3(256), 0, stream>>>(Wq, Wk, Wv, Wo, WT);
  gt_kernel<<<dim3(BT), dim3(TPB), 0, stream>>>(
      X, adj, dist, bq, bk, bv, bo, rel, WT, out, attn);
}